// Round 2
// baseline (240.471 us; speedup 1.0000x reference)
//
#include <hip/hip_runtime.h>

// Problem constants (match reference)
#define DVOL 256
#define NVOX (DVOL * DVOL * DVOL)   // 16,777,216 voxels
#define N_LABELS 1000

#define BLOCK   256
#define UNROLL  8                               // float4 groups per thread
#define NGROUPS (NVOX / 4)                      // 4,194,304 float4 groups
#define NBLOCKS (NGROUPS / (BLOCK * UNROLL))    // 2048 blocks

// Native vector types so nontemporal builtins work and regs map cleanly.
typedef float f32x4 __attribute__((ext_vector_type(4)));
typedef int   i32x4 __attribute__((ext_vector_type(4)));

// v3: force memory-level parallelism.
//   v2 post-mortem: VGPR_Count=24 proved the compiler re-serialized the
//   "issue all loads upfront" block to save registers -> only ~1-2 loads
//   in flight per wave -> latency-bound at 2.4 TB/s while fillBuffer hits
//   6.7 TB/s on the same trace.
//   Fix: sched_barrier(0) between the load block and the consumer block.
//   The scheduler cannot move instructions across it, so all 16
//   global_load_dwordx4 per thread are issued before the first waitcnt.
//   L/P interleaved in issue order so FIFO vmcnt retirement allows counted
//   per-k waits (consume k needs vmcnt <= 16-2(k+1)).
__global__ __launch_bounds__(BLOCK)
void vessel_fuse_kernel(const int* __restrict__ labels,
                        const int* __restrict__ keep_mask,
                        const float* __restrict__ intensity_lut,
                        const float* __restrict__ parenchyma,
                        float* __restrict__ out,      // [NVOX] float32
                        float* __restrict__ maskf)    // [NVOX] float32 (0.0/1.0)
{
    __shared__ float s_scale[N_LABELS];

    for (int l = threadIdx.x; l < N_LABELS; l += BLOCK) {
        const bool keep = (l > 0) && (keep_mask[l] > 0);
        s_scale[l] = keep ? intensity_lut[l] : 1.0f;
    }
    __syncthreads();

    const i32x4* lab4 = (const i32x4*)labels;
    const f32x4* par4 = (const f32x4*)parenchyma;
    f32x4* out4 = (f32x4*)out;
    f32x4* msk4 = (f32x4*)maskf;

    // Block-contiguous partition: block b owns groups
    // [b*BLOCK*UNROLL, (b+1)*BLOCK*UNROLL); sub-chunk k is lane-coalesced.
    const int base = blockIdx.x * (BLOCK * UNROLL) + threadIdx.x;

    i32x4 L[UNROLL];
    f32x4 P[UNROLL];
#pragma unroll
    for (int k = 0; k < UNROLL; ++k) {
        L[k] = lab4[base + k * BLOCK];
        P[k] = par4[base + k * BLOCK];
    }
    // Hard scheduling fence: nothing below may be hoisted above, nothing
    // above may sink below -> all 16 loads issued & register-resident
    // before any consumer waits. (This is what v2 was missing: without it
    // the scheduler folded the loads back into a serial load-use chain.)
    __builtin_amdgcn_sched_barrier(0);

#pragma unroll
    for (int k = 0; k < UNROLL; ++k) {
        const int idx = base + k * BLOCK;

        f32x4 s;
        s.x = s_scale[L[k].x];
        s.y = s_scale[L[k].y];
        s.z = s_scale[L[k].z];
        s.w = s_scale[L[k].w];

        f32x4 o, m;
        o.x = P[k].x * s.x;  m.x = (s.x != 1.0f) ? 1.0f : 0.0f;
        o.y = P[k].y * s.y;  m.y = (s.y != 1.0f) ? 1.0f : 0.0f;
        o.z = P[k].z * s.z;  m.z = (s.z != 1.0f) ? 1.0f : 0.0f;
        o.w = P[k].w * s.w;  m.w = (s.w != 1.0f) ? 1.0f : 0.0f;

        __builtin_nontemporal_store(o, &out4[idx]);
        __builtin_nontemporal_store(m, &msk4[idx]);
    }
}

extern "C" void kernel_launch(void* const* d_in, const int* in_sizes, int n_in,
                              void* d_out, int out_size, void* d_ws, size_t ws_size,
                              hipStream_t stream) {
    (void)in_sizes; (void)n_in; (void)d_ws; (void)ws_size; (void)out_size;

    const int*   vessel_labels = (const int*)d_in[0];   // [D,D,D] int32
    const int*   keep_mask     = (const int*)d_in[1];   // [N_LABELS] int32
    const float* intensity_lut = (const float*)d_in[2]; // [N_LABELS] float32
    const float* parenchyma    = (const float*)d_in[3]; // [D,D,D] float32

    float* out   = (float*)d_out;          // output 0: modulated parenchyma
    float* maskf = (float*)d_out + NVOX;   // output 1: vessel mask as float

    vessel_fuse_kernel<<<NBLOCKS, BLOCK, 0, stream>>>(
        vessel_labels, keep_mask, intensity_lut, parenchyma, out, maskf);
}

// Round 4
// 229.899 us; speedup vs baseline: 1.0460x; 1.0460x over previous
//
#include <hip/hip_runtime.h>

// Problem constants (match reference)
#define DVOL 256
#define NVOX (DVOL * DVOL * DVOL)   // 16,777,216 voxels
#define N_LABELS 1000

#define BLOCK   256
#define NGROUPS (NVOX / 4)          // 4,194,304 float4 groups
#define NBLOCKS (NGROUPS / BLOCK)   // 16384 blocks, 1 float4/thread

typedef float f32x4 __attribute__((ext_vector_type(4)));
typedef int   i32x4 __attribute__((ext_vector_type(4)));

// v5: no-LDS, no-prologue, nontemporal streaming.
//
// Evidence from rounds 0-2: three structurally different kernels all ran
// 81-83 us with VALUBusy ~3%, HBM ~31%, LDS idle — and a fully L3-warm
// dispatch (FETCH ~3 MB) took the SAME time as a cold one (FETCH 65 MB).
// Time is insensitive to where reads are served from => not BW-bound;
// the load-ISSUE path is the limiter. Suspects: (1) vector-L1 outstanding-
// miss tracking serializes wave loads at the CU regardless of backing
// latency; (2) per-block LUT-stage + syncthreads prologue replayed 4096x
// with coarse ~40us blocks (occupancy stuck ~55%).
//
// Fix: build the fused 4 KB scale LUT ONCE in workspace via a tiny
// pre-kernel; main kernel is prologue-free, LDS-free: NT load ->
// L1-resident global LUT gather -> NT store. One float4 per thread,
// 16384 fine-grained blocks for max TLP.
__global__ __launch_bounds__(BLOCK)
void build_fused_lut(const int* __restrict__ keep_mask,
                     const float* __restrict__ intensity_lut,
                     float* __restrict__ fused)
{
    for (int l = threadIdx.x; l < N_LABELS; l += BLOCK) {
        const bool keep = (l > 0) && (keep_mask[l] > 0);
        // Kept intensities lie in [0,0.7) u [1.3,2): never exactly 1.0,
        // so scale==1.0f exactly encodes "not a vessel".
        fused[l] = keep ? intensity_lut[l] : 1.0f;
    }
}

__global__ __launch_bounds__(BLOCK)
void vessel_fuse_kernel(const int* __restrict__ labels,
                        const float* __restrict__ fused,      // [N_LABELS] in d_ws
                        const float* __restrict__ parenchyma,
                        float* __restrict__ out,      // [NVOX] float32
                        float* __restrict__ maskf)    // [NVOX] float32 (0.0/1.0)
{
    const int i = blockIdx.x * BLOCK + threadIdx.x;

    const i32x4 L = __builtin_nontemporal_load((const i32x4*)labels + i);
    const f32x4 P = __builtin_nontemporal_load((const f32x4*)parenchyma + i);

    f32x4 s;
    s.x = fused[L.x];       // 4 KB read-only LUT: L1-hot in every CU
    s.y = fused[L.y];
    s.z = fused[L.z];
    s.w = fused[L.w];

    f32x4 o, m;
    o.x = P.x * s.x;  m.x = (s.x != 1.0f) ? 1.0f : 0.0f;
    o.y = P.y * s.y;  m.y = (s.y != 1.0f) ? 1.0f : 0.0f;
    o.z = P.z * s.z;  m.z = (s.z != 1.0f) ? 1.0f : 0.0f;
    o.w = P.w * s.w;  m.w = (s.w != 1.0f) ? 1.0f : 0.0f;

    __builtin_nontemporal_store(o, (f32x4*)out + i);
    __builtin_nontemporal_store(m, (f32x4*)maskf + i);
}

// Fallback (workspace unavailable): round-0 proven LDS-staging kernel.
__global__ __launch_bounds__(BLOCK)
void vessel_fuse_lds(const int* __restrict__ labels,
                     const int* __restrict__ keep_mask,
                     const float* __restrict__ intensity_lut,
                     const float* __restrict__ parenchyma,
                     float* __restrict__ out,
                     float* __restrict__ maskf)
{
    __shared__ float s_scale[N_LABELS];
    for (int l = threadIdx.x; l < N_LABELS; l += BLOCK) {
        const bool keep = (l > 0) && (keep_mask[l] > 0);
        s_scale[l] = keep ? intensity_lut[l] : 1.0f;
    }
    __syncthreads();

    const i32x4* lab4 = (const i32x4*)labels;
    const f32x4* par4 = (const f32x4*)parenchyma;
    f32x4* out4 = (f32x4*)out;
    f32x4* msk4 = (f32x4*)maskf;

    const int stride = gridDim.x * blockDim.x;
    for (int i = blockIdx.x * BLOCK + threadIdx.x; i < NGROUPS; i += stride) {
        const i32x4 L = lab4[i];
        const f32x4 P = par4[i];
        f32x4 s, o, m;
        s.x = s_scale[L.x]; s.y = s_scale[L.y];
        s.z = s_scale[L.z]; s.w = s_scale[L.w];
        o.x = P.x * s.x;  m.x = (s.x != 1.0f) ? 1.0f : 0.0f;
        o.y = P.y * s.y;  m.y = (s.y != 1.0f) ? 1.0f : 0.0f;
        o.z = P.z * s.z;  m.z = (s.z != 1.0f) ? 1.0f : 0.0f;
        o.w = P.w * s.w;  m.w = (s.w != 1.0f) ? 1.0f : 0.0f;
        out4[i] = o;
        msk4[i] = m;
    }
}

extern "C" void kernel_launch(void* const* d_in, const int* in_sizes, int n_in,
                              void* d_out, int out_size, void* d_ws, size_t ws_size,
                              hipStream_t stream) {
    (void)in_sizes; (void)n_in; (void)out_size;

    const int*   vessel_labels = (const int*)d_in[0];   // [D,D,D] int32
    const int*   keep_mask     = (const int*)d_in[1];   // [N_LABELS] int32
    const float* intensity_lut = (const float*)d_in[2]; // [N_LABELS] float32
    const float* parenchyma    = (const float*)d_in[3]; // [D,D,D] float32

    float* out   = (float*)d_out;          // output 0: modulated parenchyma
    float* maskf = (float*)d_out + NVOX;   // output 1: vessel mask as float

    if (d_ws != nullptr && ws_size >= N_LABELS * sizeof(float)) {
        float* fused = (float*)d_ws;
        build_fused_lut<<<1, BLOCK, 0, stream>>>(keep_mask, intensity_lut, fused);
        vessel_fuse_kernel<<<NBLOCKS, BLOCK, 0, stream>>>(
            vessel_labels, fused, parenchyma, out, maskf);
    } else {
        vessel_fuse_lds<<<4096, BLOCK, 0, stream>>>(
            vessel_labels, keep_mask, intensity_lut, parenchyma, out, maskf);
    }
}